// Round 7
// baseline (922.515 us; speedup 1.0000x reference)
//
#include <hip/hip_runtime.h>

#define TT 8

typedef __attribute__((ext_vector_type(4))) float f32x4;
typedef __attribute__((ext_vector_type(8))) short s16x8;
typedef __attribute__((ext_vector_type(4))) unsigned u32x4;

__device__ __forceinline__ float lrelu(float x){ return fmaxf(x, 0.2f*x); }
__device__ __forceinline__ float fast_tanh(float x){
  float e = __expf(2.f*x);
  return 1.f - 2.f/(e+1.f);
}
__device__ __forceinline__ short f2b(float f){
  unsigned u = __float_as_uint(f);
  unsigned r = (u + 0x7fffu + ((u>>16)&1u)) >> 16;
  return (short)(r & 0xffffu);
}
__device__ __forceinline__ unsigned cvtpk(float lo, float hi){
  unsigned r;
  asm("v_cvt_pk_bf16_f32 %0, %1, %2" : "=v"(r) : "v"(lo), "v"(hi));
  return r;
}
__device__ __forceinline__ s16x8 u2s(u32x4 v){ return __builtin_bit_cast(s16x8, v); }

// A-fragment for v_mfma_f32_16x16x32_bf16: lane l holds A[row=l&15][k=8*(l>>4)+e],
// A(row=out col c, k=in i) = W[i][c] (W row-major [K][ldw]).
__device__ __forceinline__ s16x8 load_afrag(const float* __restrict__ W, int ldw,
                                            int k0, int c0, int l){
  s16x8 f;
  const int r = l & 15, kb = (l >> 4) * 8;
  #pragma unroll
  for(int e=0;e<8;++e) f[e] = f2b(W[(size_t)(k0 + kb + e)*ldw + c0 + r]);
  return f;
}
// aux frag: k=0 slot holds bias[c] (pairs with B-aux e0=1.0)
__device__ __forceinline__ s16x8 aux1(const float* __restrict__ b, int c0, int l){
  s16x8 f = {0,0,0,0,0,0,0,0};
  if(l < 16) f[0] = f2b(b[c0 + l]);
  return f;
}
// L1 aux: k=0 -> time row wt1[c] (B e0 = tk), k=1 -> a1[c] (B e1 = 1.0)
__device__ __forceinline__ s16x8 aux2(const float* __restrict__ wrow,
                                      const float* __restrict__ b, int c0, int l){
  s16x8 f = {0,0,0,0,0,0,0,0};
  if(l < 16){ f[0] = f2b(wrow[c0 + l]); f[1] = f2b(b[c0 + l]); }
  return f;
}
__device__ __forceinline__ s16x8 ldfrag(const short* __restrict__ FR, int f, int l){
  return *(const s16x8*)(FR + ((size_t)f*64 + l)*8);
}

// Repack: D-layout packed pairs -> next-layer B-fragment, pure shfl (no LDS/barrier).
// pk[ct][p] at lane (g,st) = bf16x2(OUT[16ct+4g+2p], OUT[16ct+4g+2p+1]) of state st.
// B-frag k-tile kt: dw[w4] = pk[2kt+(l>=32)][w4&1] @ lane ((2(g&1)+(w4>>1))<<4)|st.
__device__ __forceinline__ s16x8 bfrag(const unsigned* pkL, const unsigned* pkH,
                                       int sLo, int sHi, bool hi){
  unsigned a0 = (unsigned)__shfl((int)pkL[0], sLo), b0 = (unsigned)__shfl((int)pkH[0], sLo);
  unsigned a1 = (unsigned)__shfl((int)pkL[1], sLo), b1 = (unsigned)__shfl((int)pkH[1], sLo);
  unsigned a2 = (unsigned)__shfl((int)pkL[0], sHi), b2 = (unsigned)__shfl((int)pkH[0], sHi);
  unsigned a3 = (unsigned)__shfl((int)pkL[1], sHi), b3 = (unsigned)__shfl((int)pkH[1], sHi);
  u32x4 v = { hi?b0:a0, hi?b1:a1, hi?b2:a2, hi?b3:a3 };
  return u2s(v);
}

// Frag table decode. IVP: [0,24) L1 ct*3+{k0,k1,aux2}; [24,64) L2 ct*5+{k0..k3,aux};
// [64,84) L3 ct*5+{k0..k3,aux}. Dec rec: [84,108) rW1 ct*3+{k0,k1,aux};
// [108,128) rW2 ct*5+{k0..k3,aux}.
__device__ s16x8 make_frag(int f, int l,
    const float* A1, const float* a1, const float* A2, const float* a2,
    const float* A3, const float* a3,
    const float* rW1, const float* rb1, const float* rW2, const float* rb2){
  if(f < 24){ int ct=f/3, kt=f%3;
    if(kt<2) return load_afrag(A1,128,32*kt,16*ct,l);
    return aux2(A1+64*128, a1, 16*ct, l); }
  if(f < 64){ int q=f-24, ct=q/5, kt=q%5;
    if(kt<4) return load_afrag(A2,128,32*kt,16*ct,l);
    return aux1(a2,16*ct,l); }
  if(f < 84){ int q=f-64, ct=q/5, kt=q%5;
    if(kt<4) return load_afrag(A3,64,32*kt,16*ct,l);
    return aux1(a3,16*ct,l); }
  if(f < 108){ int q=f-84, ct=q/3, kt=q%3;
    if(kt<2) return load_afrag(rW1,128,32*kt,16*ct,l);
    return aux1(rb1,16*ct,l); }
  { int q=f-108, ct=q/5, kt=q%5;
    if(kt<4) return load_afrag(rW2,64,32*kt,16*ct,l);
    return aux1(rb2,16*ct,l); }
}

#define MFMA __builtin_amdgcn_mfma_f32_16x16x32_bf16

// One barrier-free Euler step for 16 states within one wave.
__device__ __forceinline__ void ivp_step(const short* __restrict__ FR, int l,
    int sLo, int sHi, bool hi, s16x8 bone, float tk, float adt,
    float (&z)[4][4], unsigned (&zpk)[4][2]){
  s16x8 bt = {0,0,0,0,0,0,0,0};
  if(l < 16){ bt[0] = f2b(tk); bt[1] = (short)0x3F80; }
  s16x8 zb0 = bfrag(zpk[0], zpk[1], sLo, sHi, hi);
  s16x8 zb1 = bfrag(zpk[2], zpk[3], sLo, sHi, hi);
  unsigned pk1[8][2];
  #pragma unroll
  for(int ct=0; ct<8; ++ct){
    f32x4 a = {0.f,0.f,0.f,0.f};
    a = MFMA(ldfrag(FR, ct*3+0, l), zb0, a, 0,0,0);
    a = MFMA(ldfrag(FR, ct*3+1, l), zb1, a, 0,0,0);
    a = MFMA(ldfrag(FR, ct*3+2, l), bt,  a, 0,0,0);
    float h0=fast_tanh(a[0]), h1=fast_tanh(a[1]), h2=fast_tanh(a[2]), h3=fast_tanh(a[3]);
    pk1[ct][0]=cvtpk(h0,h1); pk1[ct][1]=cvtpk(h2,h3);
  }
  s16x8 hb[4];
  #pragma unroll
  for(int kt=0;kt<4;++kt) hb[kt] = bfrag(pk1[2*kt], pk1[2*kt+1], sLo, sHi, hi);
  unsigned pk2[8][2];
  #pragma unroll
  for(int ct=0; ct<8; ++ct){
    f32x4 a = {0.f,0.f,0.f,0.f};
    #pragma unroll
    for(int kt=0;kt<4;++kt) a = MFMA(ldfrag(FR, 24+ct*5+kt, l), hb[kt], a, 0,0,0);
    a = MFMA(ldfrag(FR, 24+ct*5+4, l), bone, a, 0,0,0);
    float h0=fast_tanh(a[0]), h1=fast_tanh(a[1]), h2=fast_tanh(a[2]), h3=fast_tanh(a[3]);
    pk2[ct][0]=cvtpk(h0,h1); pk2[ct][1]=cvtpk(h2,h3);
  }
  s16x8 gb[4];
  #pragma unroll
  for(int kt=0;kt<4;++kt) gb[kt] = bfrag(pk2[2*kt], pk2[2*kt+1], sLo, sHi, hi);
  #pragma unroll
  for(int ct=0; ct<4; ++ct){
    f32x4 a = {0.f,0.f,0.f,0.f};
    #pragma unroll
    for(int kt=0;kt<4;++kt) a = MFMA(ldfrag(FR, 64+ct*5+kt, l), gb[kt], a, 0,0,0);
    a = MFMA(ldfrag(FR, 64+ct*5+4, l), bone, a, 0,0,0);
    #pragma unroll
    for(int r=0;r<4;++r) z[ct][r] = fmaf(adt, a[r], z[ct][r]);
    zpk[ct][0]=cvtpk(z[ct][0],z[ct][1]); zpk[ct][1]=cvtpk(z[ct][2],z[ct][3]);
  }
}

// ---------------- Encoder: 128 blocks x 128 thr (2 waves, same t, 16 samples each)
extern "C" __global__ void __launch_bounds__(128)
k_enc(const float* __restrict__ features,
      const float* __restrict__ feW1, const float* __restrict__ feb1,
      const float* __restrict__ feW2, const float* __restrict__ feb2,
      const float* __restrict__ feW3, const float* __restrict__ feb3,
      const float* __restrict__ A1, const float* __restrict__ a1,
      const float* __restrict__ A2, const float* __restrict__ a2,
      const float* __restrict__ A3, const float* __restrict__ a3,
      const float* __restrict__ pW1, const float* __restrict__ pb1,
      const float* __restrict__ pW2, const float* __restrict__ pb2,
      float* __restrict__ ws_mu, float* __restrict__ ws_lv)
{
  __shared__ __align__(16) short FR[84*64*8];
  __shared__ float zcolS[2][64][16];
  __shared__ float hcolS[2][64][16];
  const int tid = threadIdx.x, l = tid & 63, w = tid >> 6;
  const int g = l >> 4, st = l & 15;
  const int sLo = ((g & 1) * 2) * 16 + st, sHi = sLo + 16;
  const bool hi = (l >= 32);
  const int t_blk = blockIdx.x & 7, chunk = blockIdx.x >> 3;
  const int s0w = chunk*32 + w*16;

  for(int f = w; f < 84; f += 2)
    *(s16x8*)(FR + ((size_t)f*64 + l)*8) =
      make_frag(f, l, A1,a1,A2,a2,A3,a3, nullptr,nullptr,nullptr,nullptr);
  __syncthreads();

  s16x8 bone = {0,0,0,0,0,0,0,0};
  if(l < 16) bone[0] = (short)0x3F80;

  // ---- embedding (wave-local MFMA; bias folded at k=6 of E1 frag) ----
  s16x8 bf = {0,0,0,0,0,0,0,0};
  if(l < 16){
    const float* fp = features + ((size_t)(s0w + l)*TT + t_blk)*6;
    #pragma unroll
    for(int e=0;e<6;++e) bf[e] = f2b(fp[e]);
    bf[6] = (short)0x3F80;
  }
  unsigned pkE1[8][2];
  #pragma unroll
  for(int ct=0; ct<8; ++ct){
    s16x8 af = {0,0,0,0,0,0,0,0};
    { const int r = l & 15, kb = (l>>4)*8;
      #pragma unroll
      for(int e=0;e<8;++e){
        int k = kb + e;
        if(k < 6) af[e] = f2b(feW1[k*128 + 16*ct + r]);
        else if(k == 6) af[e] = f2b(feb1[16*ct + r]);
      } }
    f32x4 a = {0.f,0.f,0.f,0.f};
    a = MFMA(af, bf, a, 0,0,0);
    pkE1[ct][0] = cvtpk(lrelu(a[0]), lrelu(a[1]));
    pkE1[ct][1] = cvtpk(lrelu(a[2]), lrelu(a[3]));
  }
  unsigned pkE2[4][2];
  {
    s16x8 bin[4];
    #pragma unroll
    for(int kt=0;kt<4;++kt) bin[kt] = bfrag(pkE1[2*kt], pkE1[2*kt+1], sLo, sHi, hi);
    #pragma unroll
    for(int ct=0; ct<4; ++ct){
      f32x4 a = {0.f,0.f,0.f,0.f};
      #pragma unroll
      for(int kt=0;kt<4;++kt) a = MFMA(load_afrag(feW2,64,32*kt,16*ct,l), bin[kt], a, 0,0,0);
      a = MFMA(aux1(feb2,16*ct,l), bone, a, 0,0,0);
      pkE2[ct][0] = cvtpk(lrelu(a[0]), lrelu(a[1]));
      pkE2[ct][1] = cvtpk(lrelu(a[2]), lrelu(a[3]));
    }
  }
  float z[4][4];
  unsigned zpk[4][2];
  {
    s16x8 b0f = bfrag(pkE2[0], pkE2[1], sLo, sHi, hi);
    s16x8 b1f = bfrag(pkE2[2], pkE2[3], sLo, sHi, hi);
    #pragma unroll
    for(int ct=0; ct<4; ++ct){
      f32x4 a = {0.f,0.f,0.f,0.f};
      a = MFMA(load_afrag(feW3,64, 0,16*ct,l), b0f, a, 0,0,0);
      a = MFMA(load_afrag(feW3,64,32,16*ct,l), b1f, a, 0,0,0);
      a = MFMA(aux1(feb3,16*ct,l), bone, a, 0,0,0);
      #pragma unroll
      for(int r=0;r<4;++r) z[ct][r] = a[r];
      zpk[ct][0]=cvtpk(z[ct][0],z[ct][1]); zpk[ct][1]=cvtpk(z[ct][2],z[ct][3]);
    }
  }

  // ---- IVP: 10*t barrier-free steps (adt=-0.1, t_k=0.1k) ----
  const int steps = 10 * t_blk;
  for(int k=0; k<steps; ++k)
    ivp_step(FR, l, sLo, sHi, hi, bone, 0.1f*(float)k, -0.1f, z, zpk);

  // ---- posterior: f32 (precision-critical), via wave-region LDS + block barriers ----
  #pragma unroll
  for(int ct=0;ct<4;++ct)
    #pragma unroll
    for(int r=0;r<4;++r) zcolS[w][16*ct+4*g+r][st] = z[ct][r];
  __syncthreads();
  #pragma unroll 2
  for(int cc=0; cc<16; ++cc){
    int c = 16*g + cc;
    float acc = pb1[c];
    #pragma unroll 8
    for(int i=0;i<64;++i) acc = fmaf(zcolS[w][i][st], pW1[i*64+c], acc);
    hcolS[w][c][st] = lrelu(acc);
  }
  __syncthreads();
  #pragma unroll 2
  for(int cc=0; cc<32; ++cc){
    int c = 32*g + cc;
    float acc = pb2[c];
    #pragma unroll 8
    for(int i=0;i<64;++i) acc = fmaf(hcolS[w][i][st], pW2[i*128+c], acc);
    size_t o = ((size_t)(s0w + st)*TT + t_blk)*64;
    if(c < 64) ws_mu[o + c] = acc;
    else       ws_lv[o + c - 64] = acc;
  }
}

// Inline reconstruction for one t from current zpk (wave-local, no barriers).
__device__ __forceinline__ void rec_t(const short* __restrict__ FR, int l,
    int sLo, int sHi, bool hi, s16x8 bone, const unsigned (&zpk)[4][2],
    const float* __restrict__ rW3, const float* __restrict__ rb3,
    float* __restrict__ out, int b0, int w, int t){
  s16x8 b0f = bfrag(zpk[0], zpk[1], sLo, sHi, hi);
  s16x8 b1f = bfrag(zpk[2], zpk[3], sLo, sHi, hi);
  unsigned pkh[8][2];
  #pragma unroll
  for(int ct=0; ct<8; ++ct){
    f32x4 a = {0.f,0.f,0.f,0.f};
    a = MFMA(ldfrag(FR, 84+ct*3+0, l), b0f, a, 0,0,0);
    a = MFMA(ldfrag(FR, 84+ct*3+1, l), b1f, a, 0,0,0);
    a = MFMA(ldfrag(FR, 84+ct*3+2, l), bone, a, 0,0,0);
    pkh[ct][0] = cvtpk(lrelu(a[0]), lrelu(a[1]));
    pkh[ct][1] = cvtpk(lrelu(a[2]), lrelu(a[3]));
  }
  s16x8 hb[4];
  #pragma unroll
  for(int kt=0;kt<4;++kt) hb[kt] = bfrag(pkh[2*kt], pkh[2*kt+1], sLo, sHi, hi);
  const int g = l>>4, st = l&15;
  float p0 = 0.f, p1 = 0.f;
  #pragma unroll
  for(int ct=0; ct<4; ++ct){
    f32x4 a = {0.f,0.f,0.f,0.f};
    #pragma unroll
    for(int kt=0;kt<4;++kt) a = MFMA(ldfrag(FR, 108+ct*5+kt, l), hb[kt], a, 0,0,0);
    a = MFMA(ldfrag(FR, 108+ct*5+4, l), bone, a, 0,0,0);
    #pragma unroll
    for(int r=0;r<4;++r){
      float h = lrelu(a[r]);
      const float* wv = rW3 + (16*ct + 4*g + r)*2;
      p0 = fmaf(h, wv[0], p0);
      p1 = fmaf(h, wv[1], p1);
    }
  }
  p0 += __shfl_xor(p0, 16); p0 += __shfl_xor(p0, 32);
  p1 += __shfl_xor(p1, 16); p1 += __shfl_xor(p1, 32);
  if(l < 16){
    int s_l = w*16 + l;
    float* op = out + ((size_t)(b0 + s_l)*TT + t)*2;
    op[0] = p0 + rb3[0];
    op[1] = p1 + rb3[1];
  }
}

// ---------------- Decoder: 16 blocks x 128 thr (2 waves x 16 samples)
extern "C" __global__ void __launch_bounds__(128)
k_dec(const float* __restrict__ mu_g, const float* __restrict__ lv_g,
      const float* __restrict__ eps,
      const float* __restrict__ mxW1, const float* __restrict__ mxb1,
      const float* __restrict__ mxW2, const float* __restrict__ mxb2,
      const float* __restrict__ A1, const float* __restrict__ a1,
      const float* __restrict__ A2, const float* __restrict__ a2,
      const float* __restrict__ A3, const float* __restrict__ a3,
      const float* __restrict__ rW1, const float* __restrict__ rb1,
      const float* __restrict__ rW2, const float* __restrict__ rb2,
      const float* __restrict__ rW3, const float* __restrict__ rb3,
      float* __restrict__ out)
{
  __shared__ __align__(16) short FR[128*64*8];
  __shared__ float wlS[256];
  __shared__ float wsmS[32][8];
  const int tid = threadIdx.x, l = tid & 63, w = tid >> 6;
  const int g = l >> 4, st = l & 15;
  const int sLo = ((g & 1) * 2) * 16 + st, sHi = sLo + 16;
  const bool hi = (l >= 32);
  const int b0 = blockIdx.x * 32;

  for(int f = w; f < 128; f += 2)
    *(s16x8*)(FR + ((size_t)f*64 + l)*8) =
      make_frag(f, l, A1,a1,A2,a2,A3,a3, rW1,rb1,rW2,rb2);

  // ---- mixing logits (f32; 2 pairs/thread) ----
  for(int pp=0; pp<2; ++pp){
    int p = tid + pp*128;
    int s_l = p >> 3, t = p & 7;
    const float* mrow = mu_g + ((size_t)(b0 + s_l)*TT + t)*64;
    float acc[32];
    #pragma unroll
    for(int c=0;c<32;++c) acc[c] = mxb1[c];
    #pragma unroll 4
    for(int i=0;i<64;++i){
      float m = mrow[i];
      #pragma unroll
      for(int c=0;c<32;++c) acc[c] = fmaf(m, mxW1[i*32+c], acc[c]);
    }
    float wl = mxb2[0];
    #pragma unroll
    for(int c=0;c<32;++c) wl = fmaf(lrelu(acc[c]), mxW2[c], wl);
    wlS[p] = wl;
  }
  __syncthreads();
  if(tid < 32){
    float m = -1e30f;
    #pragma unroll
    for(int t=0;t<8;++t) m = fmaxf(m, wlS[tid*8+t]);
    float e[8], S = 0.f;
    #pragma unroll
    for(int t=0;t<8;++t){ e[t] = __expf(wlS[tid*8+t]-m); S += e[t]; }
    float inv = 1.f/S;
    #pragma unroll
    for(int t=0;t<8;++t) wsmS[tid][t] = e[t]*inv;
  }
  __syncthreads();

  s16x8 bone = {0,0,0,0,0,0,0,0};
  if(l < 16) bone[0] = (short)0x3F80;

  // ---- z0: f32 reparameterization (lane owns its 16 cols of its state) ----
  float z[4][4];
  unsigned zpk[4][2];
  {
    const int s_l = w*16 + st;
    float wsv[8];
    #pragma unroll
    for(int t=0;t<8;++t) wsv[t] = wsmS[s_l][t];
    #pragma unroll
    for(int ct=0; ct<4; ++ct){
      #pragma unroll
      for(int r=0;r<4;++r){
        int c = 16*ct + 4*g + r;
        float mu0 = 0.f, lv0 = 0.f;
        #pragma unroll
        for(int t=0;t<8;++t){
          size_t o = ((size_t)(b0 + s_l)*TT + t)*64 + c;
          mu0 = fmaf(wsv[t], mu_g[o], mu0);
          lv0 = fmaf(wsv[t], lv_g[o], lv0);
        }
        z[ct][r] = fmaf(eps[(size_t)(b0 + s_l)*64 + c], __expf(0.5f*lv0), mu0);
      }
      zpk[ct][0]=cvtpk(z[ct][0],z[ct][1]); zpk[ct][1]=cvtpk(z[ct][2],z[ct][3]);
    }
  }

  // ---- t=0 reconstruction, then shared 70-step trajectory with inline rec ----
  rec_t(FR, l, sLo, sHi, hi, bone, zpk, rW3, rb3, out, b0, w, 0);
  for(int k=0; k<70; ++k){
    ivp_step(FR, l, sLo, sHi, hi, bone, 0.1f*(float)k, 0.1f, z, zpk);
    if(((k+1) % 10) == 0)
      rec_t(FR, l, sLo, sHi, hi, bone, zpk, rW3, rb3, out, b0, w, (k+1)/10);
  }
}

extern "C" void kernel_launch(void* const* d_in, const int* in_sizes, int n_in,
                              void* d_out, int out_size, void* d_ws, size_t ws_size,
                              hipStream_t stream){
  const float* features=(const float*)d_in[0];
  const float* eps     =(const float*)d_in[1];
  const float* feW1=(const float*)d_in[2];  const float* feb1=(const float*)d_in[3];
  const float* feW2=(const float*)d_in[4];  const float* feb2=(const float*)d_in[5];
  const float* feW3=(const float*)d_in[6];  const float* feb3=(const float*)d_in[7];
  const float* eA1=(const float*)d_in[8];   const float* ea1=(const float*)d_in[9];
  const float* eA2=(const float*)d_in[10];  const float* ea2=(const float*)d_in[11];
  const float* eA3=(const float*)d_in[12];  const float* ea3=(const float*)d_in[13];
  const float* pW1=(const float*)d_in[14];  const float* pb1=(const float*)d_in[15];
  const float* pW2=(const float*)d_in[16];  const float* pb2=(const float*)d_in[17];
  const float* mxW1=(const float*)d_in[18]; const float* mxb1=(const float*)d_in[19];
  const float* mxW2=(const float*)d_in[20]; const float* mxb2=(const float*)d_in[21];
  const float* dA1=(const float*)d_in[22];  const float* da1=(const float*)d_in[23];
  const float* dA2=(const float*)d_in[24];  const float* da2=(const float*)d_in[25];
  const float* dA3=(const float*)d_in[26];  const float* da3=(const float*)d_in[27];
  const float* rW1=(const float*)d_in[28];  const float* rb1=(const float*)d_in[29];
  const float* rW2=(const float*)d_in[30];  const float* rb2=(const float*)d_in[31];
  const float* rW3=(const float*)d_in[32];  const float* rb3=(const float*)d_in[33];

  float* ws_mu=(float*)d_ws;
  float* ws_lv=ws_mu + 512*8*64;

  k_enc<<<dim3(128),dim3(128),0,stream>>>(features,
      feW1,feb1,feW2,feb2,feW3,feb3,
      eA1,ea1,eA2,ea2,eA3,ea3,
      pW1,pb1,pW2,pb2,
      ws_mu, ws_lv);
  k_dec<<<dim3(16),dim3(128),0,stream>>>(ws_mu, ws_lv, eps,
      mxW1,mxb1,mxW2,mxb2,
      dA1,da1,dA2,da2,dA3,da3,
      rW1,rb1,rW2,rb2,rW3,rb3,
      (float*)d_out);
}

// Round 8
// 668.051 us; speedup vs baseline: 1.3809x; 1.3809x over previous
//
#include <hip/hip_runtime.h>

#define TT 8

typedef __attribute__((ext_vector_type(4))) float f32x4;
typedef __attribute__((ext_vector_type(8))) short s16x8;
typedef __attribute__((ext_vector_type(4))) short s16x4;

__device__ __forceinline__ float lrelu(float x){ return fmaxf(x, 0.2f*x); }
__device__ __forceinline__ float fast_tanh(float x){
  float e = __expf(2.f*x);
  return 1.f - 2.f/(e+1.f);
}
__device__ __forceinline__ short f2b(float f){
  unsigned u = __float_as_uint(f);
  unsigned r = (u + 0x7fffu + ((u>>16)&1u)) >> 16;
  return (short)(r & 0xffffu);
}

// A-fragment for v_mfma_f32_16x16x32_bf16: lane l holds A[row=l&15][k=8*(l>>4)+e].
// A(row=out col c, k=in i) = W[i][c] (W row-major [K][ldw]).
__device__ __forceinline__ s16x8 load_afrag(const float* __restrict__ W, int ldw,
                                            int k0, int c0, int l){
  s16x8 f;
  const int r = l & 15, kb = (l >> 4) * 8;
  #pragma unroll
  for(int e=0;e<8;++e) f[e] = f2b(W[(size_t)(k0 + kb + e)*ldw + c0 + r]);
  return f;
}

// Per-wave weights in VGPRs: wave-col-tile wct owns out-cols [16wct,16wct+16)
// of L1/L2 (8 tiles), and (if wct<4) of L3.
struct Frags {
  s16x8 a1f[2];            // L1: K=64 -> 2 k-tiles
  s16x8 a2f[4];            // L2: K=128 -> 4 k-tiles
  s16x8 a3f[4];            // L3 (wct<4): K=128
  float wt1[4], b1[4], b2[4], b3[4];
};

__device__ __forceinline__ void load_frags(Frags& F,
    const float* __restrict__ A1, const float* __restrict__ a1,
    const float* __restrict__ A2, const float* __restrict__ a2,
    const float* __restrict__ A3, const float* __restrict__ a3,
    int wct, int l){
  const int h = l >> 4;
  #pragma unroll
  for(int kt=0;kt<2;++kt) F.a1f[kt] = load_afrag(A1, 128, 32*kt, 16*wct, l);
  #pragma unroll
  for(int kt=0;kt<4;++kt) F.a2f[kt] = load_afrag(A2, 128, 32*kt, 16*wct, l);
  #pragma unroll
  for(int r=0;r<4;++r){
    const int c = 16*wct + 4*h + r;
    F.wt1[r] = A1[64*128 + c];   // time row (A1 is 65x128)
    F.b1[r]  = a1[c];
    F.b2[r]  = a2[c];
  }
  if(wct < 4){
    #pragma unroll
    for(int kt=0;kt<4;++kt) F.a3f[kt] = load_afrag(A3, 64, 32*kt, 16*wct, l);
    #pragma unroll
    for(int r=0;r<4;++r) F.b3[r] = a3[16*wct + 4*h + r];
  }
}

// One Euler step for this wave's 16-state group. Packed-bf16 LDS B layout:
// row(k,st)=((k>>3)<<4)|st, elem k&7; lane l of k-tile kt reads row 64kt+l as
// one b128. D k-row 16wct+4h+r packs to row (2wct+(h>>1))*16+st, elem 4(h&1)+r.
// z lives in zreg on waves wct<4. 3 block barriers per step (16 waves, 2 groups).
__device__ __forceinline__ void ivp_step(const Frags& F, int wct, int grp, int l,
    float tk, float adt, float (&zreg)[4],
    short* __restrict__ zBg, short* __restrict__ h1pg, short* __restrict__ h2pg,
    float* __restrict__ latBase){
  const int h = l>>4, st = l&15;
  const int wrow = (2*wct + (h>>1))*16 + st;
  const int we = 4*(h&1);
  // ---- L1: z(64) -> h1(128) ----
  {
    s16x8 bz0 = *(const s16x8*)(zBg + (size_t)l*8);
    s16x8 bz1 = *(const s16x8*)(zBg + (size_t)(64+l)*8);
    f32x4 acc = {0.f,0.f,0.f,0.f};
    acc = __builtin_amdgcn_mfma_f32_16x16x32_bf16(F.a1f[0], bz0, acc, 0,0,0);
    acc = __builtin_amdgcn_mfma_f32_16x16x32_bf16(F.a1f[1], bz1, acc, 0,0,0);
    s16x4 pk;
    #pragma unroll
    for(int r=0;r<4;++r) pk[r] = f2b(fast_tanh(fmaf(tk, F.wt1[r], acc[r]) + F.b1[r]));
    *(s16x4*)(h1pg + (size_t)wrow*8 + we) = pk;
  }
  __syncthreads();
  // ---- L2: h1(128) -> h2(128) ----
  {
    f32x4 acc = {0.f,0.f,0.f,0.f};
    #pragma unroll
    for(int kt=0;kt<4;++kt){
      s16x8 b = *(const s16x8*)(h1pg + (size_t)(64*kt + l)*8);
      acc = __builtin_amdgcn_mfma_f32_16x16x32_bf16(F.a2f[kt], b, acc, 0,0,0);
    }
    s16x4 pk;
    #pragma unroll
    for(int r=0;r<4;++r) pk[r] = f2b(fast_tanh(acc[r] + F.b2[r]));
    *(s16x4*)(h2pg + (size_t)wrow*8 + we) = pk;
  }
  __syncthreads();
  // ---- L3: h2(128) -> dz(64); Euler update on waves wct<4 ----
  if(wct < 4){
    f32x4 acc = {0.f,0.f,0.f,0.f};
    #pragma unroll
    for(int kt=0;kt<4;++kt){
      s16x8 b = *(const s16x8*)(h2pg + (size_t)(64*kt + l)*8);
      acc = __builtin_amdgcn_mfma_f32_16x16x32_bf16(F.a3f[kt], b, acc, 0,0,0);
    }
    s16x4 pk;
    #pragma unroll
    for(int r=0;r<4;++r){
      zreg[r] = fmaf(adt, acc[r] + F.b3[r], zreg[r]);
      pk[r] = f2b(zreg[r]);
    }
    *(s16x4*)(zBg + (size_t)wrow*8 + we) = pk;
    if(latBase){
      #pragma unroll
      for(int r=0;r<4;++r) latBase[(16*wct + 4*h + r)*33 + grp*16 + st] = zreg[r];
    }
  }
  __syncthreads();
}

// ---------------- Encoder ----------------
// 128 blocks x 1024 thr (16 waves). block = (32-sample chunk) x (single t);
// two 16-state groups (grp = w&1), uniform 10*t steps. LDS padded >80KB -> 1 block/CU.
extern "C" __global__ void __launch_bounds__(1024, 4)
k_enc(const float* __restrict__ features,
      const float* __restrict__ feW1, const float* __restrict__ feb1,
      const float* __restrict__ feW2, const float* __restrict__ feb2,
      const float* __restrict__ feW3, const float* __restrict__ feb3,
      const float* __restrict__ A1, const float* __restrict__ a1,
      const float* __restrict__ A2, const float* __restrict__ a2,
      const float* __restrict__ A3, const float* __restrict__ a3,
      const float* __restrict__ pW1, const float* __restrict__ pb1,
      const float* __restrict__ pW2, const float* __restrict__ pb2,
      float* __restrict__ ws_mu, float* __restrict__ ws_lv)
{
  __shared__ __align__(16) short zB[2*128*8];
  __shared__ __align__(16) short h1p[2*256*8];
  __shared__ __align__(16) short h2p[2*256*8];
  __shared__ float featS[32][6];
  __shared__ float hE1[128*33];
  __shared__ float hE2[64*33];
  __shared__ float zE[64*33];
  __shared__ float pad_lds[7040];   // occupancy pad: force 1 block/CU (>80KB total)
  const int tid = threadIdx.x, l = tid & 63, w = tid >> 6;   // 16 waves
  const int wct = w >> 1, grp = w & 1;
  const int c1 = tid & 127, sh = tid >> 7;                   // sh in [0,8)
  const int q = w;                                           // 2-state slot owner
  const int t_blk = blockIdx.x & 7, chunk = blockIdx.x >> 3, s0 = chunk*32;
  if(gridDim.y == 7u) pad_lds[tid & 1023] = 1.f;             // never true; keeps pad live

  short* zBg  = zB  + (size_t)grp*128*8;
  short* h1pg = h1p + (size_t)grp*256*8;
  short* h2pg = h2p + (size_t)grp*256*8;

  Frags F;
  load_frags(F, A1, a1, A2, a2, A3, a3, wct, l);

  if(tid < 192){
    int e = tid / 6, i = tid - 6*e;
    featS[e][i] = features[((size_t)(s0+e)*TT + t_blk)*6 + i];
  }
  __syncthreads();
  // E1: 6 -> 128 (4 states/thread)
  {
    float acc[4]; const float b = feb1[c1];
    #pragma unroll
    for(int e=0;e<4;++e) acc[e]=b;
    #pragma unroll
    for(int i=0;i<6;++i){
      const float wv = feW1[i*128 + c1];
      #pragma unroll
      for(int e=0;e<4;++e) acc[e] = fmaf(featS[4*sh+e][i], wv, acc[e]);
    }
    #pragma unroll
    for(int e=0;e<4;++e) hE1[c1*33 + 4*sh+e] = lrelu(acc[e]);
  }
  __syncthreads();
  // E2: 128 -> 64 (2 states/thread)
  {
    float acc[2]; const float b = feb2[l];
    acc[0]=b; acc[1]=b;
    for(int i=0;i<128;++i){
      const float wv = feW2[i*64 + l];
      acc[0] = fmaf(hE1[i*33 + 2*q  ], wv, acc[0]);
      acc[1] = fmaf(hE1[i*33 + 2*q+1], wv, acc[1]);
    }
    hE2[l*33 + 2*q  ] = lrelu(acc[0]);
    hE2[l*33 + 2*q+1] = lrelu(acc[1]);
  }
  __syncthreads();
  // E3: 64 -> 64 (linear)
  {
    float acc[2]; const float b = feb3[l];
    acc[0]=b; acc[1]=b;
    for(int i=0;i<64;++i){
      const float wv = feW3[i*64 + l];
      acc[0] = fmaf(hE2[i*33 + 2*q  ], wv, acc[0]);
      acc[1] = fmaf(hE2[i*33 + 2*q+1], wv, acc[1]);
    }
    zE[l*33 + 2*q  ] = acc[0];
    zE[l*33 + 2*q+1] = acc[1];
  }
  __syncthreads();
  // init z registers + packed zB (owner waves wct<4, per group)
  float zreg[4] = {0.f,0.f,0.f,0.f};
  if(wct < 4){
    const int h=l>>4, st=l&15;
    s16x4 pk;
    #pragma unroll
    for(int r=0;r<4;++r){ zreg[r] = zE[(16*wct+4*h+r)*33 + grp*16+st]; pk[r]=f2b(zreg[r]); }
    *(s16x4*)(zBg + (size_t)((2*wct+(h>>1))*16+st)*8 + 4*(h&1)) = pk;
  }
  __syncthreads();

  const int steps = 10 * t_blk;
  for(int k=0; k<steps; ++k)
    ivp_step(F, wct, grp, l, 0.1f*(float)k, -0.1f, zreg, zBg, h1pg, h2pg, nullptr);

  // z back to f32 LDS
  if(wct < 4){
    const int h=l>>4, st=l&15;
    #pragma unroll
    for(int r=0;r<4;++r) zE[(16*wct+4*h+r)*33 + grp*16+st] = zreg[r];
  }
  __syncthreads();
  // posterior L1: 64 -> 64 (2 states/thread)
  {
    float acc[2]; const float b = pb1[l];
    acc[0]=b; acc[1]=b;
    for(int i=0;i<64;++i){
      const float wv = pW1[i*64 + l];
      acc[0] = fmaf(zE[i*33 + 2*q  ], wv, acc[0]);
      acc[1] = fmaf(zE[i*33 + 2*q+1], wv, acc[1]);
    }
    hE2[l*33 + 2*q  ] = lrelu(acc[0]);
    hE2[l*33 + 2*q+1] = lrelu(acc[1]);
  }
  __syncthreads();
  // posterior L2: 64 -> 128 (mu | lv), 4 states/thread
  {
    float acc[4]; const float b = pb2[c1];
    #pragma unroll
    for(int e=0;e<4;++e) acc[e]=b;
    for(int i=0;i<64;++i){
      const float wv = pW2[i*128 + c1];
      #pragma unroll
      for(int e=0;e<4;++e) acc[e] = fmaf(hE2[i*33 + 4*sh+e], wv, acc[e]);
    }
    #pragma unroll
    for(int e=0;e<4;++e){
      const int s = s0 + 4*sh + e;
      const size_t o = ((size_t)s*TT + t_blk)*64;
      if(c1 < 64) ws_mu[o + c1] = acc[e];
      else        ws_lv[o + c1 - 64] = acc[e];
    }
  }
}

// ---------------- Decoder ----------------
// 16 blocks x 1024 thr, 32 samples each (2 groups of 16). mix+softmax+reparam;
// ONE shared 70-step trajectory (all _ivp(z0,t) prefixes), snapshot every 10; rec MLP.
extern "C" __global__ void __launch_bounds__(1024, 4)
k_dec(const float* __restrict__ mu_g, const float* __restrict__ lv_g,
      const float* __restrict__ eps,
      const float* __restrict__ mxW1, const float* __restrict__ mxb1,
      const float* __restrict__ mxW2, const float* __restrict__ mxb2,
      const float* __restrict__ A1, const float* __restrict__ a1,
      const float* __restrict__ A2, const float* __restrict__ a2,
      const float* __restrict__ A3, const float* __restrict__ a3,
      const float* __restrict__ rW1, const float* __restrict__ rb1,
      const float* __restrict__ rW2, const float* __restrict__ rb2,
      const float* __restrict__ rW3, const float* __restrict__ rb3,
      float* __restrict__ out)
{
  __shared__ __align__(16) short zB[2*128*8];
  __shared__ __align__(16) short h1p[2*256*8];
  __shared__ __align__(16) short h2p[2*256*8];
  __shared__ float pool[8448];          // mh [(s*8+t)*33+c]; later hR1/hR2
  __shared__ float LATS[8*64*33];       // [t][col*33 + state]
  __shared__ float wlS[256];
  __shared__ float wsmS[32][8];
  const int tid = threadIdx.x, l = tid & 63, w = tid >> 6;
  const int wct = w >> 1, grp = w & 1;
  const int c1 = tid & 127, sh = tid >> 7;
  const int q = w;
  const int b0 = blockIdx.x * 32;

  short* zBg  = zB  + (size_t)grp*128*8;
  short* h1pg = h1p + (size_t)grp*256*8;
  short* h2pg = h2p + (size_t)grp*256*8;

  Frags F;
  load_frags(F, A1, a1, A2, a2, A3, a3, wct, l);

  // mixing hidden: 32s x 8t x 32c = 8192 items
  for(int p=0; p<8; ++p){
    int idx = tid + p*1024;
    int s = idx>>8, t = (idx>>5)&7, c = idx&31;
    float a = mxb1[c];
    #pragma unroll 8
    for(int i=0;i<64;++i) a = fmaf(mu_g[((size_t)(b0+s)*TT + t)*64 + i], mxW1[i*32+c], a);
    pool[(s*8+t)*33 + c] = lrelu(a);
  }
  __syncthreads();
  if(tid < 256){
    int s = tid>>3, t = tid&7;
    float a = mxb2[0];
    #pragma unroll
    for(int i=0;i<32;++i) a = fmaf(pool[(s*8+t)*33 + i], mxW2[i], a);
    wlS[tid] = a;
  }
  __syncthreads();
  if(tid < 32){
    float m = -1e30f;
    #pragma unroll
    for(int t=0;t<8;++t) m = fmaxf(m, wlS[tid*8+t]);
    float e[8], S = 0.f;
    #pragma unroll
    for(int t=0;t<8;++t){ e[t] = __expf(wlS[tid*8+t]-m); S += e[t]; }
    const float inv = 1.f/S;
    #pragma unroll
    for(int t=0;t<8;++t) wsmS[tid][t] = e[t]*inv;
  }
  __syncthreads();
  // z0 (f32 reparameterization) on owner waves
  float zreg[4] = {0.f,0.f,0.f,0.f};
  if(wct < 4){
    const int h=l>>4, st=l&15, sidx = grp*16+st;
    float wsv[8];
    #pragma unroll
    for(int t=0;t<8;++t) wsv[t] = wsmS[sidx][t];
    s16x4 pk;
    #pragma unroll
    for(int r=0;r<4;++r){
      const int c = 16*wct + 4*h + r;
      float mu0 = 0.f, lv0 = 0.f;
      #pragma unroll
      for(int t=0;t<8;++t){
        size_t o = ((size_t)(b0+sidx)*TT + t)*64 + c;
        mu0 = fmaf(wsv[t], mu_g[o], mu0);
        lv0 = fmaf(wsv[t], lv_g[o], lv0);
      }
      const float z0 = fmaf(eps[(size_t)(b0+sidx)*64 + c], __expf(0.5f*lv0), mu0);
      zreg[r] = z0; pk[r] = f2b(z0);
      LATS[c*33 + sidx] = z0;
    }
    *(s16x4*)(zBg + (size_t)((2*wct+(h>>1))*16+st)*8 + 4*(h&1)) = pk;
  }
  __syncthreads();

  for(int k=0; k<70; ++k){
    float* latBase = (((k+1)%10)==0) ? (LATS + ((k+1)/10)*64*33) : nullptr;
    ivp_step(F, wct, grp, l, 0.1f*(float)k, 0.1f, zreg, zBg, h1pg, h2pg, latBase);
  }

  // reconstruction MLP per t (f32; hR1/hR2 alias pool)
  float* hR1 = pool;                 // [col c1][state], stride 33
  float* hR2 = pool + 128*33;        // [state][col], stride 65
  for(int t=0;t<TT;++t){
    {
      float acc[4]; const float b = rb1[c1];
      #pragma unroll
      for(int e=0;e<4;++e) acc[e]=b;
      for(int i=0;i<64;++i){
        const float wv = rW1[i*128 + c1];
        #pragma unroll
        for(int e=0;e<4;++e) acc[e] = fmaf(LATS[t*2112 + i*33 + 4*sh+e], wv, acc[e]);
      }
      #pragma unroll
      for(int e=0;e<4;++e) hR1[c1*33 + 4*sh + e] = lrelu(acc[e]);
    }
    __syncthreads();
    {
      float acc[2]; const float b = rb2[l];
      acc[0]=b; acc[1]=b;
      for(int i=0;i<128;++i){
        const float wv = rW2[i*64 + l];
        acc[0] = fmaf(hR1[i*33 + 2*q  ], wv, acc[0]);
        acc[1] = fmaf(hR1[i*33 + 2*q+1], wv, acc[1]);
      }
      hR2[(2*q  )*65 + l] = lrelu(acc[0]);
      hR2[(2*q+1)*65 + l] = lrelu(acc[1]);
    }
    __syncthreads();
    if(tid < 64){
      const int s = tid >> 1, o = tid & 1;
      float a = rb3[o];
      for(int i=0;i<64;++i) a = fmaf(hR2[s*65 + i], rW3[i*2 + o], a);
      out[((size_t)(b0+s)*TT + t)*2 + o] = a;
    }
    __syncthreads();
  }
}

extern "C" void kernel_launch(void* const* d_in, const int* in_sizes, int n_in,
                              void* d_out, int out_size, void* d_ws, size_t ws_size,
                              hipStream_t stream){
  const float* features=(const float*)d_in[0];
  const float* eps     =(const float*)d_in[1];
  const float* feW1=(const float*)d_in[2];  const float* feb1=(const float*)d_in[3];
  const float* feW2=(const float*)d_in[4];  const float* feb2=(const float*)d_in[5];
  const float* feW3=(const float*)d_in[6];  const float* feb3=(const float*)d_in[7];
  const float* eA1=(const float*)d_in[8];   const float* ea1=(const float*)d_in[9];
  const float* eA2=(const float*)d_in[10];  const float* ea2=(const float*)d_in[11];
  const float* eA3=(const float*)d_in[12];  const float* ea3=(const float*)d_in[13];
  const float* pW1=(const float*)d_in[14];  const float* pb1=(const float*)d_in[15];
  const float* pW2=(const float*)d_in[16];  const float* pb2=(const float*)d_in[17];
  const float* mxW1=(const float*)d_in[18]; const float* mxb1=(const float*)d_in[19];
  const float* mxW2=(const float*)d_in[20]; const float* mxb2=(const float*)d_in[21];
  const float* dA1=(const float*)d_in[22];  const float* da1=(const float*)d_in[23];
  const float* dA2=(const float*)d_in[24];  const float* da2=(const float*)d_in[25];
  const float* dA3=(const float*)d_in[26];  const float* da3=(const float*)d_in[27];
  const float* rW1=(const float*)d_in[28];  const float* rb1=(const float*)d_in[29];
  const float* rW2=(const float*)d_in[30];  const float* rb2=(const float*)d_in[31];
  const float* rW3=(const float*)d_in[32];  const float* rb3=(const float*)d_in[33];

  float* ws_mu=(float*)d_ws;
  float* ws_lv=ws_mu + 512*8*64;

  k_enc<<<dim3(128),dim3(1024),0,stream>>>(features,
      feW1,feb1,feW2,feb2,feW3,feb3,
      eA1,ea1,eA2,ea2,eA3,ea3,
      pW1,pb1,pW2,pb2,
      ws_mu, ws_lv);
  k_dec<<<dim3(16),dim3(1024),0,stream>>>(ws_mu, ws_lv, eps,
      mxW1,mxb1,mxW2,mxb2,
      dA1,da1,dA2,da2,dA3,da3,
      rW1,rb1,rW2,rb2,rW3,rb3,
      (float*)d_out);
}

// Round 9
// 323.962 us; speedup vs baseline: 2.8476x; 2.0621x over previous
//
#include <hip/hip_runtime.h>

#define TT 8

typedef __attribute__((ext_vector_type(4))) float f32x4;
typedef __attribute__((ext_vector_type(8))) short s16x8;
typedef __attribute__((ext_vector_type(4))) short s16x4;

__device__ __forceinline__ float lrelu(float x){ return fmaxf(x, 0.2f*x); }
__device__ __forceinline__ float fast_tanh(float x){
  float e = __expf(2.f*x);
  return 1.f - 2.f/(e+1.f);
}
__device__ __forceinline__ short f2b(float f){
  unsigned u = __float_as_uint(f);
  unsigned r = (u + 0x7fffu + ((u>>16)&1u)) >> 16;
  return (short)(r & 0xffffu);
}

// A-fragment for v_mfma_f32_16x16x32_bf16: lane l holds A[row=l&15][k=8*(l>>4)+e].
// A(row=out col c, k=in i) = W[i][c] (W row-major [K][ldw]).
__device__ __forceinline__ s16x8 load_afrag(const float* __restrict__ W, int ldw,
                                            int k0, int c0, int l){
  s16x8 f;
  const int r = l & 15, kb = (l >> 4) * 8;
  #pragma unroll
  for(int e=0;e<8;++e) f[e] = f2b(W[(size_t)(k0 + kb + e)*ldw + c0 + r]);
  return f;
}

// Per-wave weights in VGPRs: wave w owns out-cols [16w,16w+16) of L1/L2 (8 waves),
// and (if w<4) out-cols [16w,16w+16) of L3.
struct Frags {
  s16x8 a1f[2];            // L1: K=64 -> 2 k-tiles
  s16x8 a2f[4];            // L2: K=128 -> 4 k-tiles
  s16x8 a3f[4];            // L3 (w<4): K=128
  float wt1[4], b1[4], b2[4], b3[4];
};

__device__ __forceinline__ void load_frags(Frags& F,
    const float* __restrict__ A1, const float* __restrict__ a1,
    const float* __restrict__ A2, const float* __restrict__ a2,
    const float* __restrict__ A3, const float* __restrict__ a3,
    int w, int l){
  const int h = l >> 4;
  #pragma unroll
  for(int kt=0;kt<2;++kt) F.a1f[kt] = load_afrag(A1, 128, 32*kt, 16*w, l);
  #pragma unroll
  for(int kt=0;kt<4;++kt) F.a2f[kt] = load_afrag(A2, 128, 32*kt, 16*w, l);
  #pragma unroll
  for(int r=0;r<4;++r){
    const int c = 16*w + 4*h + r;
    F.wt1[r] = A1[64*128 + c];   // time row (A1 is 65x128)
    F.b1[r]  = a1[c];
    F.b2[r]  = a2[c];
  }
  if(w < 4){
    #pragma unroll
    for(int kt=0;kt<4;++kt) F.a3f[kt] = load_afrag(A3, 64, 32*kt, 16*w, l);
    #pragma unroll
    for(int r=0;r<4;++r) F.b3[r] = a3[16*w + 4*h + r];
  }
}

// One Euler step for 16 states. Packed-bf16 LDS B layout: row(k,st)=((k>>3)<<4)|st,
// elem k&7; lane l of k-tile kt reads row 64*kt+l as one b128. D k-row 16w+4h+r
// packs to row (2w+(h>>1))*16+st, elem 4(h&1)+r. z lives in zreg on waves 0-3.
__device__ __forceinline__ void ivp_step(const Frags& F, int w, int l,
    float tk, float adt, float (&zreg)[4],
    short* __restrict__ zB, short* __restrict__ h1p, short* __restrict__ h2p,
    float* __restrict__ latRow){
  const int h = l>>4, st = l&15;
  const int wrow = (2*w + (h>>1))*16 + st;
  const int welem = 4*(h&1);
  // ---- L1: z(64) -> h1(128) ----
  {
    s16x8 bz0 = *(const s16x8*)(zB + (size_t)l*8);
    s16x8 bz1 = *(const s16x8*)(zB + (size_t)(64+l)*8);
    f32x4 acc = {0.f,0.f,0.f,0.f};
    acc = __builtin_amdgcn_mfma_f32_16x16x32_bf16(F.a1f[0], bz0, acc, 0,0,0);
    acc = __builtin_amdgcn_mfma_f32_16x16x32_bf16(F.a1f[1], bz1, acc, 0,0,0);
    s16x4 pk;
    #pragma unroll
    for(int r=0;r<4;++r) pk[r] = f2b(fast_tanh(fmaf(tk, F.wt1[r], acc[r]) + F.b1[r]));
    *(s16x4*)(h1p + (size_t)wrow*8 + welem) = pk;
  }
  __syncthreads();
  // ---- L2: h1(128) -> h2(128) ----
  {
    f32x4 acc = {0.f,0.f,0.f,0.f};
    #pragma unroll
    for(int kt=0;kt<4;++kt){
      s16x8 b = *(const s16x8*)(h1p + (size_t)(64*kt + l)*8);
      acc = __builtin_amdgcn_mfma_f32_16x16x32_bf16(F.a2f[kt], b, acc, 0,0,0);
    }
    s16x4 pk;
    #pragma unroll
    for(int r=0;r<4;++r) pk[r] = f2b(fast_tanh(acc[r] + F.b2[r]));
    *(s16x4*)(h2p + (size_t)wrow*8 + welem) = pk;
  }
  __syncthreads();
  // ---- L3: h2(128) -> dz(64); Euler update on waves 0-3 ----
  if(w < 4){
    f32x4 acc = {0.f,0.f,0.f,0.f};
    #pragma unroll
    for(int kt=0;kt<4;++kt){
      s16x8 b = *(const s16x8*)(h2p + (size_t)(64*kt + l)*8);
      acc = __builtin_amdgcn_mfma_f32_16x16x32_bf16(F.a3f[kt], b, acc, 0,0,0);
    }
    s16x4 pk;
    #pragma unroll
    for(int r=0;r<4;++r){
      zreg[r] = fmaf(adt, acc[r] + F.b3[r], zreg[r]);
      pk[r] = f2b(zreg[r]);
    }
    *(s16x4*)(zB + (size_t)wrow*8 + welem) = pk;
    if(latRow){
      #pragma unroll
      for(int r=0;r<4;++r) latRow[(16*w + 4*h + r)*16 + st] = zreg[r];
    }
  }
  __syncthreads();
}

// ---------------- Encoder ----------------
// 256 blocks x 512 thr. block = (16-sample chunk) x (single t); 10*t uniform steps.
// LDS padded >80KB so only ONE block fits per CU: stops the command processor
// from co-packing t=4..7 blocks on one CU (that packing was the 197us makespan).
extern "C" __global__ void __launch_bounds__(512, 2)
k_enc(const float* __restrict__ features,
      const float* __restrict__ feW1, const float* __restrict__ feb1,
      const float* __restrict__ feW2, const float* __restrict__ feb2,
      const float* __restrict__ feW3, const float* __restrict__ feb3,
      const float* __restrict__ A1, const float* __restrict__ a1,
      const float* __restrict__ A2, const float* __restrict__ a2,
      const float* __restrict__ A3, const float* __restrict__ a3,
      const float* __restrict__ pW1, const float* __restrict__ pb1,
      const float* __restrict__ pW2, const float* __restrict__ pb2,
      float* __restrict__ ws_mu, float* __restrict__ ws_lv)
{
  __shared__ __align__(16) short zB[128*8];
  __shared__ __align__(16) short h1p[256*8];
  __shared__ __align__(16) short h2p[256*8];
  __shared__ float featS[16][6];
  __shared__ float hE1[128][16];
  __shared__ float hE2[64][16];
  __shared__ float zE[64][16];
  __shared__ float occ_pad[14336];   // 56KB pad -> total ~83KB -> 1 block/CU
  const int tid = threadIdx.x, l = tid & 63, w = tid >> 6;      // 8 waves
  const int c1 = tid & 127, sh = tid >> 7;                      // sh in [0,4)
  const int t_blk = blockIdx.x & 7, chunk = blockIdx.x >> 3, s0 = chunk*16;

  occ_pad[tid] = 0.f;                       // touch pad
  Frags F;
  load_frags(F, A1, a1, A2, a2, A3, a3, w, l);

  if(tid < 96){
    int e = tid / 6, i = tid - 6*e;
    featS[e][i] = features[((size_t)(s0+e)*TT + t_blk)*6 + i];
  }
  __syncthreads();
  // E1: 6 -> 128 (4 states/thread)
  {
    float acc[4]; const float b = feb1[c1];
    #pragma unroll
    for(int e=0;e<4;++e) acc[e]=b;
    #pragma unroll
    for(int i=0;i<6;++i){
      const float wv = feW1[i*128 + c1];
      #pragma unroll
      for(int e=0;e<4;++e) acc[e] = fmaf(featS[4*sh+e][i], wv, acc[e]);
    }
    #pragma unroll
    for(int e=0;e<4;++e) hE1[c1][4*sh+e] = lrelu(acc[e]);
  }
  __syncthreads();
  // E2: 128 -> 64 (2 states/thread)
  {
    float acc[2]; const float b = feb2[l];
    acc[0]=b; acc[1]=b;
    for(int i=0;i<128;++i){
      const float wv = feW2[i*64 + l];
      acc[0] = fmaf(hE1[i][2*w  ], wv, acc[0]);
      acc[1] = fmaf(hE1[i][2*w+1], wv, acc[1]);
    }
    hE2[l][2*w  ] = lrelu(acc[0]);
    hE2[l][2*w+1] = lrelu(acc[1]);
  }
  __syncthreads();
  // E3: 64 -> 64 (linear)
  {
    float acc[2]; const float b = feb3[l];
    acc[0]=b; acc[1]=b;
    for(int i=0;i<64;++i){
      const float wv = feW3[i*64 + l];
      acc[0] = fmaf(hE2[i][2*w  ], wv, acc[0]);
      acc[1] = fmaf(hE2[i][2*w+1], wv, acc[1]);
    }
    zE[l][2*w  ] = acc[0];
    zE[l][2*w+1] = acc[1];
  }
  __syncthreads();
  // init z registers + packed zB (waves 0-3)
  float zreg[4] = {0.f,0.f,0.f,0.f};
  if(w < 4){
    const int h=l>>4, st=l&15;
    s16x4 pk;
    #pragma unroll
    for(int r=0;r<4;++r){ zreg[r] = zE[16*w+4*h+r][st]; pk[r]=f2b(zreg[r]); }
    *(s16x4*)(zB + (size_t)((2*w+(h>>1))*16+st)*8 + 4*(h&1)) = pk;
  }
  __syncthreads();

  const int steps = 10*t_blk;
  for(int k=0;k<steps;++k)
    ivp_step(F, w, l, 0.1f*(float)k, -0.1f, zreg, zB, h1p, h2p, nullptr);

  // z back to f32 LDS
  if(w < 4){
    const int h=l>>4, st=l&15;
    #pragma unroll
    for(int r=0;r<4;++r) zE[16*w+4*h+r][st] = zreg[r];
  }
  __syncthreads();
  // posterior L1: 64 -> 64 (2 states/thread)
  {
    float acc[2]; const float b = pb1[l];
    acc[0]=b; acc[1]=b;
    for(int i=0;i<64;++i){
      const float wv = pW1[i*64 + l];
      acc[0] = fmaf(zE[i][2*w  ], wv, acc[0]);
      acc[1] = fmaf(zE[i][2*w+1], wv, acc[1]);
    }
    hE2[l][2*w  ] = lrelu(acc[0]);
    hE2[l][2*w+1] = lrelu(acc[1]);
  }
  __syncthreads();
  // posterior L2: 64 -> 128 (mu | lv), 4 states/thread
  {
    float acc[4]; const float b = pb2[c1];
    #pragma unroll
    for(int e=0;e<4;++e) acc[e]=b;
    for(int i=0;i<64;++i){
      const float wv = pW2[i*128 + c1];
      #pragma unroll
      for(int e=0;e<4;++e) acc[e] = fmaf(hE2[i][4*sh+e], wv, acc[e]);
    }
    #pragma unroll
    for(int e=0;e<4;++e){
      const int s = s0 + 4*sh + e;
      const size_t o = ((size_t)s*TT + t_blk)*64;
      if(c1 < 64) ws_mu[o + c1] = acc[e];
      else        ws_lv[o + c1 - 64] = acc[e];
    }
  }
  // keep occ_pad live: never-taken guard the compiler cannot fold away
  if(gridDim.y == 7u) ws_mu[0] = occ_pad[tid];
}

// ---------------- Decoder ----------------
// 32 blocks x 512 thr, 16 samples each; ONE shared 70-step trajectory
// (all _ivp(z0,t) are prefixes), snapshot every 10 steps; rec MLP.
// Unchanged from the 325us round (proven 124us, 1 block/CU via 125KB LDS).
extern "C" __global__ void __launch_bounds__(512, 2)
k_dec(const float* __restrict__ mu_g, const float* __restrict__ lv_g,
      const float* __restrict__ eps,
      const float* __restrict__ mxW1, const float* __restrict__ mxb1,
      const float* __restrict__ mxW2, const float* __restrict__ mxb2,
      const float* __restrict__ A1, const float* __restrict__ a1,
      const float* __restrict__ A2, const float* __restrict__ a2,
      const float* __restrict__ A3, const float* __restrict__ a3,
      const float* __restrict__ rW1, const float* __restrict__ rb1,
      const float* __restrict__ rW2, const float* __restrict__ rb2,
      const float* __restrict__ rW3, const float* __restrict__ rb3,
      float* __restrict__ out)
{
  __shared__ __align__(16) short zB[128*8];
  __shared__ __align__(16) short h1p[256*8];
  __shared__ __align__(16) short h2p[256*8];
  __shared__ float muB[16*8*64];   // reused as hR1/hR2 in rec phase
  __shared__ float lvB[16*8*64];
  __shared__ float mh[16][8][32];
  __shared__ float LATS[TT][64][16];
  __shared__ float wsm[16][8];
  const int tid = threadIdx.x, l = tid & 63, w = tid >> 6;
  const int c1 = tid & 127, sh = tid >> 7;
  const int b0 = blockIdx.x * 16;

  for(int idx=tid; idx<8192; idx+=512){
    muB[idx] = mu_g[(size_t)b0*512 + idx];
    lvB[idx] = lv_g[(size_t)b0*512 + idx];
  }
  Frags F;
  load_frags(F, A1, a1, A2, a2, A3, a3, w, l);
  __syncthreads();

  // mixing hidden (parallel: 4096 items / 512 thr)
  for(int idx=tid; idx<4096; idx+=512){
    const int s = idx>>8, t = (idx>>5)&7, c = idx&31;
    float a = mxb1[c];
    #pragma unroll 8
    for(int i=0;i<64;++i) a = fmaf(muB[(s*8+t)*64+i], mxW1[i*32+c], a);
    mh[s][t][c] = lrelu(a);
  }
  __syncthreads();
  if(tid < 128){
    const int s = tid>>3, t = tid&7;
    float a = mxb2[0];
    #pragma unroll
    for(int i=0;i<32;++i) a = fmaf(mh[s][t][i], mxW2[i], a);
    wsm[s][t] = a;
  }
  __syncthreads();
  if(tid < 16){
    float m = -1e30f;
    #pragma unroll
    for(int t=0;t<8;++t) m = fmaxf(m, wsm[tid][t]);
    float e[8], S=0.f;
    #pragma unroll
    for(int t=0;t<8;++t){ e[t] = __expf(wsm[tid][t]-m); S += e[t]; }
    const float inv = 1.f/S;
    #pragma unroll
    for(int t=0;t<8;++t) wsm[tid][t] = e[t]*inv;
  }
  __syncthreads();
  // z0 (reparameterized) on waves 0-3
  float zreg[4] = {0.f,0.f,0.f,0.f};
  if(w < 4){
    const int h=l>>4, st=l&15;
    s16x4 pk;
    #pragma unroll
    for(int r=0;r<4;++r){
      const int c = 16*w + 4*h + r;
      float mu0=0.f, lv0=0.f;
      #pragma unroll
      for(int t=0;t<8;++t){
        const float wv = wsm[st][t];
        mu0 = fmaf(wv, muB[(st*8+t)*64 + c], mu0);
        lv0 = fmaf(wv, lvB[(st*8+t)*64 + c], lv0);
      }
      const float z0 = fmaf(eps[(size_t)(b0+st)*64 + c], __expf(0.5f*lv0), mu0);
      zreg[r] = z0; pk[r] = f2b(z0);
      LATS[0][c][st] = z0;
    }
    *(s16x4*)(zB + (size_t)((2*w+(h>>1))*16+st)*8 + 4*(h&1)) = pk;
  }
  __syncthreads();

  for(int k=0;k<70;++k){
    float* latRow = (((k+1)%10)==0) ? &LATS[(k+1)/10][0][0] : nullptr;
    ivp_step(F, w, l, 0.1f*(float)k, 0.1f, zreg, zB, h1p, h2p, latRow);
  }

  // reconstruction MLP per t (f32; hR1/hR2 alias muB)
  float* hR1 = muB;            // [128][16]
  float* hR2 = muB + 128*16;   // [64][16]
  for(int t=0;t<TT;++t){
    {
      float acc[4]; const float b = rb1[c1];
      #pragma unroll
      for(int e=0;e<4;++e) acc[e]=b;
      for(int i=0;i<64;++i){
        const float wv = rW1[i*128 + c1];
        #pragma unroll
        for(int e=0;e<4;++e) acc[e] = fmaf(LATS[t][i][4*sh+e], wv, acc[e]);
      }
      #pragma unroll
      for(int e=0;e<4;++e) hR1[c1*16 + 4*sh + e] = lrelu(acc[e]);
    }
    __syncthreads();
    {
      float acc[2]; const float b = rb2[l];
      acc[0]=b; acc[1]=b;
      for(int i=0;i<128;++i){
        const float wv = rW2[i*64 + l];
        acc[0] = fmaf(hR1[i*16 + 2*w  ], wv, acc[0]);
        acc[1] = fmaf(hR1[i*16 + 2*w+1], wv, acc[1]);
      }
      hR2[l*16 + 2*w  ] = lrelu(acc[0]);
      hR2[l*16 + 2*w+1] = lrelu(acc[1]);
    }
    __syncthreads();
    if(tid < 32){
      const int s = tid >> 1, o = tid & 1;
      float a = rb3[o];
      for(int i=0;i<64;++i) a = fmaf(hR2[i*16 + s], rW3[i*2 + o], a);
      out[((size_t)(b0+s)*TT + t)*2 + o] = a;
    }
    __syncthreads();
  }
}

extern "C" void kernel_launch(void* const* d_in, const int* in_sizes, int n_in,
                              void* d_out, int out_size, void* d_ws, size_t ws_size,
                              hipStream_t stream){
  const float* features=(const float*)d_in[0];
  const float* eps     =(const float*)d_in[1];
  const float* feW1=(const float*)d_in[2];  const float* feb1=(const float*)d_in[3];
  const float* feW2=(const float*)d_in[4];  const float* feb2=(const float*)d_in[5];
  const float* feW3=(const float*)d_in[6];  const float* feb3=(const float*)d_in[7];
  const float* eA1=(const float*)d_in[8];   const float* ea1=(const float*)d_in[9];
  const float* eA2=(const float*)d_in[10];  const float* ea2=(const float*)d_in[11];
  const float* eA3=(const float*)d_in[12];  const float* ea3=(const float*)d_in[13];
  const float* pW1=(const float*)d_in[14];  const float* pb1=(const float*)d_in[15];
  const float* pW2=(const float*)d_in[16];  const float* pb2=(const float*)d_in[17];
  const float* mxW1=(const float*)d_in[18]; const float* mxb1=(const float*)d_in[19];
  const float* mxW2=(const float*)d_in[20]; const float* mxb2=(const float*)d_in[21];
  const float* dA1=(const float*)d_in[22];  const float* da1=(const float*)d_in[23];
  const float* dA2=(const float*)d_in[24];  const float* da2=(const float*)d_in[25];
  const float* dA3=(const float*)d_in[26];  const float* da3=(const float*)d_in[27];
  const float* rW1=(const float*)d_in[28];  const float* rb1=(const float*)d_in[29];
  const float* rW2=(const float*)d_in[30];  const float* rb2=(const float*)d_in[31];
  const float* rW3=(const float*)d_in[32];  const float* rb3=(const float*)d_in[33];

  float* ws_mu=(float*)d_ws;
  float* ws_lv=ws_mu + 512*8*64;

  k_enc<<<dim3(256),dim3(512),0,stream>>>(features,
      feW1,feb1,feW2,feb2,feW3,feb3,
      eA1,ea1,eA2,ea2,eA3,ea3,
      pW1,pb1,pW2,pb2,
      ws_mu, ws_lv);
  k_dec<<<dim3(32),dim3(512),0,stream>>>(ws_mu, ws_lv, eps,
      mxW1,mxb1,mxW2,mxb2,
      dA1,da1,dA2,da2,dA3,da3,
      rW1,rb1,rW2,rb2,rW3,rb3,
      (float*)d_out);
}